// Round 7
// baseline (854.628 us; speedup 1.0000x reference)
//
#include <hip/hip_runtime.h>
#include <cstdint>

typedef unsigned short ushort_t;
typedef __attribute__((ext_vector_type(8))) short short8;   // 8 bf16 in 4 VGPRs (guide §3)
typedef __attribute__((ext_vector_type(4))) float floatx4;

#define HID    5120
#define NHEAD  16
#define NOPE   128
#define ROPE_D 64
#define VDIM   128
#define QHD    192
#define QLORA  1536
#define KVLORA 512
#define SEQ    2048
#define PAST   2048
#define TOTK   4096
#define NQAKV  2112                     /* 1536 + 576 merged N */
#define EPS_RMS 1e-6f
#define SCALE_DEV 0.125f
#define LOG2E 1.4426950408889634f
#define ATT_SCALE 0.07216878364870322f   /* 1/sqrt(192) */
#define LOG2_10000 13.287712379549449f

__device__ __forceinline__ float bf2f(ushort_t u) {
  unsigned int x = ((unsigned int)u) << 16;
  return __builtin_bit_cast(float, x);
}
__device__ __forceinline__ ushort_t f2bf(float f) {
  unsigned int u = __builtin_bit_cast(unsigned int, f);
  unsigned int r = u + 0x7fffu + ((u >> 16) & 1u);   // RNE
  return (ushort_t)(r >> 16);
}
__device__ __forceinline__ void unpack8(uint4 c, float* f) {
  const ushort_t* p = (const ushort_t*)&c;
#pragma unroll
  for (int i = 0; i < 8; ++i) f[i] = bf2f(p[i]);
}
__device__ __forceinline__ uint4 pack8(const float* f) {
  uint4 c;
  ushort_t* p = (ushort_t*)&c;
#pragma unroll
  for (int i = 0; i < 8; ++i) p[i] = f2bf(f[i]);
  return c;
}

// fp32 -> bf16 bulk convert, 8 elems/thread, exact grid (n % 8 == 0)
__global__ void cvt_kernel(const float* __restrict__ src, ushort_t* __restrict__ dst)
{
  long i = ((long)blockIdx.x * 256 + threadIdx.x) * 8;
  float f[8];
  *(float4*)(f)     = *(const float4*)(src + i);
  *(float4*)(f + 4) = *(const float4*)(src + i + 4);
  *(uint4*)(dst + i) = pack8(f);
}

// zero a buffer, 16B/thread, exact grid
__global__ void zero4_kernel(uint4* __restrict__ dst)
{
  long i = (long)blockIdx.x * 256 + threadIdx.x;
  uint4 z; z.x = 0u; z.y = 0u; z.z = 0u; z.w = 0u;
  dst[i] = z;
}

// out0 = SCALE_DEV * hidden (residual pre-init; g5 split-K atomics add onto it)
__global__ void resid_init_kernel(const float* __restrict__ hidden,
                                  float* __restrict__ out0)
{
  long i = ((long)blockIdx.x * 256 + threadIdx.x) * 4;
  float4 v = *(const float4*)(hidden + i);
  v.x *= SCALE_DEV; v.y *= SCALE_DEV; v.z *= SCALE_DEV; v.w *= SCALE_DEV;
  *(float4*)(out0 + i) = v;
}

// ---------------------------------------------------------------------------
// GEMM: C(MxN) = A(MxK,bf16,row-major) @ B(NxK,bf16,row-major)^T
// R0 structure: 128x128 tile, BK=32, 4 waves x 4x4 16x16x32 MFMAs, padded LDS
// (stride 40 -> 2-way reads, free), VGPR prefetch of next K-slab.
// Retained for g4 only (bf16 out; grid 512 = 2.0/CU is grid-capped anyway).
// ---------------------------------------------------------------------------
#define GLDT 40
__global__ __launch_bounds__(256, 2) void gemm_bt(
    const ushort_t* __restrict__ A, const ushort_t* __restrict__ B,
    ushort_t* __restrict__ Cb, float* __restrict__ Cf,
    const float* __restrict__ resid, float resid_scale,
    int M, int N, int K)
{
  __shared__ __align__(16) ushort_t As[128 * GLDT];
  __shared__ __align__(16) ushort_t Bs[128 * GLDT];
  int t = threadIdx.x;
  int lane = t & 63, wave = t >> 6;
  int wm = wave >> 1, wn = wave & 1;
  int lrow = lane & 15, quad = lane >> 4;
  long bm = (long)blockIdx.y * 128;
  long bn = (long)blockIdx.x * 128;

  int r0 = t >> 2, cc = t & 3;
  int r1 = r0 + 64;
  const ushort_t* a0 = A + (bm + r0) * (long)K + cc * 8;
  const ushort_t* a1 = A + (bm + r1) * (long)K + cc * 8;
  long nb0 = bn + r0; if (nb0 > N - 1) nb0 = N - 1;
  long nb1 = bn + r1; if (nb1 > N - 1) nb1 = N - 1;
  const ushort_t* b0 = B + nb0 * (long)K + cc * 8;
  const ushort_t* b1 = B + nb1 * (long)K + cc * 8;

  floatx4 acc[4][4];
#pragma unroll
  for (int i = 0; i < 4; ++i)
#pragma unroll
    for (int j = 0; j < 4; ++j) acc[i][j] = (floatx4)0.f;

  uint4 pa0 = *(const uint4*)a0;
  uint4 pa1 = *(const uint4*)a1;
  uint4 pb0 = *(const uint4*)b0;
  uint4 pb1 = *(const uint4*)b1;

  int nk = K >> 5;
  for (int kt = 0; kt < nk; ++kt) {
    *(uint4*)&As[r0 * GLDT + cc * 8] = pa0;
    *(uint4*)&As[r1 * GLDT + cc * 8] = pa1;
    *(uint4*)&Bs[r0 * GLDT + cc * 8] = pb0;
    *(uint4*)&Bs[r1 * GLDT + cc * 8] = pb1;
    __syncthreads();
    if (kt + 1 < nk) {
      int off = (kt + 1) << 5;
      pa0 = *(const uint4*)(a0 + off);
      pa1 = *(const uint4*)(a1 + off);
      pb0 = *(const uint4*)(b0 + off);
      pb1 = *(const uint4*)(b1 + off);
    }
    short8 af[4], bfr[4];
#pragma unroll
    for (int mt = 0; mt < 4; ++mt)
      af[mt] = *(const short8*)&As[(wm * 64 + mt * 16 + lrow) * GLDT + quad * 8];
#pragma unroll
    for (int nt = 0; nt < 4; ++nt)
      bfr[nt] = *(const short8*)&Bs[(wn * 64 + nt * 16 + lrow) * GLDT + quad * 8];
#pragma unroll
    for (int mt = 0; mt < 4; ++mt)
#pragma unroll
      for (int nt = 0; nt < 4; ++nt)
        acc[mt][nt] = __builtin_amdgcn_mfma_f32_16x16x32_bf16(af[mt], bfr[nt], acc[mt][nt], 0, 0, 0);
    __syncthreads();
  }

#pragma unroll
  for (int mt = 0; mt < 4; ++mt) {
    long grow = bm + wm * 64 + mt * 16 + quad * 4;
#pragma unroll
    for (int nt = 0; nt < 4; ++nt) {
      long gcol = bn + wn * 64 + nt * 16 + lrow;
      if (gcol < N) {
#pragma unroll
        for (int r2 = 0; r2 < 4; ++r2) {
          long row = grow + r2;
          float v = acc[mt][nt][r2];
          if (Cf) {
            if (resid) v += resid_scale * resid[row * (long)N + gcol];
            Cf[row * (long)N + gcol] = v;
          } else {
            Cb[row * (long)N + gcol] = f2bf(v);
          }
        }
      }
    }
  }
}

// ---------------------------------------------------------------------------
// Generalized split-K GEMM: blockIdx.z picks a K-slice (remainder-aware, so
// any gridDim.z works); fp32 partials atomicAdd into pre-initialized C.
// Deterministic modulo fp32-add commutativity (proven R6; tolerance-safe).
// Used for merged qa|kva (z=3, 816 blocks), qb (z=2, 768), w_o (z=2, 1280) --
// grid inflation is the lever (R4/R6 theory: these GEMMs are grid-starved).
// ---------------------------------------------------------------------------
__global__ __launch_bounds__(256, 2) void gemm_splitk(
    const ushort_t* __restrict__ A, const ushort_t* __restrict__ B,
    float* __restrict__ Cf, int M, int N, int K)
{
  __shared__ __align__(16) ushort_t As[128 * GLDT];
  __shared__ __align__(16) ushort_t Bs[128 * GLDT];
  int t = threadIdx.x;
  int lane = t & 63, wave = t >> 6;
  int wm = wave >> 1, wn = wave & 1;
  int lrow = lane & 15, quad = lane >> 4;
  long bm = (long)blockIdx.y * 128;
  long bn = (long)blockIdx.x * 128;

  // remainder-aware K-slice: nkTot K-steps split across gridDim.z
  int nkTot = K >> 5;
  int z = blockIdx.z, nz = gridDim.z;
  int q = nkTot / nz, rsd = nkTot % nz;
  int nk = q + (z < rsd ? 1 : 0);
  int kt0 = z * q + (z < rsd ? z : rsd);
  long k0 = (long)kt0 << 5;

  int r0 = t >> 2, cc = t & 3;
  int r1 = r0 + 64;
  const ushort_t* a0 = A + (bm + r0) * (long)K + k0 + cc * 8;
  const ushort_t* a1 = A + (bm + r1) * (long)K + k0 + cc * 8;
  long nb0 = bn + r0; if (nb0 > N - 1) nb0 = N - 1;
  long nb1 = bn + r1; if (nb1 > N - 1) nb1 = N - 1;
  const ushort_t* b0 = B + nb0 * (long)K + k0 + cc * 8;
  const ushort_t* b1 = B + nb1 * (long)K + k0 + cc * 8;

  floatx4 acc[4][4];
#pragma unroll
  for (int i = 0; i < 4; ++i)
#pragma unroll
    for (int j = 0; j < 4; ++j) acc[i][j] = (floatx4)0.f;

  uint4 pa0 = *(const uint4*)a0;
  uint4 pa1 = *(const uint4*)a1;
  uint4 pb0 = *(const uint4*)b0;
  uint4 pb1 = *(const uint4*)b1;

  for (int kt = 0; kt < nk; ++kt) {
    *(uint4*)&As[r0 * GLDT + cc * 8] = pa0;
    *(uint4*)&As[r1 * GLDT + cc * 8] = pa1;
    *(uint4*)&Bs[r0 * GLDT + cc * 8] = pb0;
    *(uint4*)&Bs[r1 * GLDT + cc * 8] = pb1;
    __syncthreads();
    if (kt + 1 < nk) {
      int off = (kt + 1) << 5;
      pa0 = *(const uint4*)(a0 + off);
      pa1 = *(const uint4*)(a1 + off);
      pb0 = *(const uint4*)(b0 + off);
      pb1 = *(const uint4*)(b1 + off);
    }
    short8 af[4], bfr[4];
#pragma unroll
    for (int mt = 0; mt < 4; ++mt)
      af[mt] = *(const short8*)&As[(wm * 64 + mt * 16 + lrow) * GLDT + quad * 8];
#pragma unroll
    for (int nt = 0; nt < 4; ++nt)
      bfr[nt] = *(const short8*)&Bs[(wn * 64 + nt * 16 + lrow) * GLDT + quad * 8];
#pragma unroll
    for (int mt = 0; mt < 4; ++mt)
#pragma unroll
      for (int nt = 0; nt < 4; ++nt)
        acc[mt][nt] = __builtin_amdgcn_mfma_f32_16x16x32_bf16(af[mt], bfr[nt], acc[mt][nt], 0, 0, 0);
    __syncthreads();
  }

#pragma unroll
  for (int mt = 0; mt < 4; ++mt) {
    long grow = bm + wm * 64 + mt * 16 + quad * 4;
#pragma unroll
    for (int nt = 0; nt < 4; ++nt) {
      long gcol = bn + wn * 64 + nt * 16 + lrow;
      if (gcol < N) {
#pragma unroll
        for (int r2 = 0; r2 < 4; ++r2)
          atomicAdd(&Cf[(grow + r2) * (long)N + gcol], acc[mt][nt][r2]);
      }
    }
  }
}

// ---------------------------------------------------------------------------
// RMSNorm kernels
// ---------------------------------------------------------------------------
__global__ void rms_in_kernel(const float* __restrict__ x,
                              const float* __restrict__ w,
                              ushort_t* __restrict__ out)
{
  int row = blockIdx.x, t = threadIdx.x;  // 320 threads, 16 elems each
  const float* xr = x + (long)row * HID + t * 16;
  float v[16];
#pragma unroll
  for (int i = 0; i < 4; ++i) *(float4*)(v + i * 4) = *(const float4*)(xr + i * 4);
  float ss = 0.f;
#pragma unroll
  for (int i = 0; i < 16; ++i) ss += v[i] * v[i];
#pragma unroll
  for (int o = 1; o < 64; o <<= 1) ss += __shfl_xor(ss, o);
  __shared__ float red[5];
  if ((t & 63) == 0) red[t >> 6] = ss;
  __syncthreads();
  float tot = red[0] + red[1] + red[2] + red[3] + red[4];
  float sc = rsqrtf(tot / (float)HID + EPS_RMS);
  float wv[16];
#pragma unroll
  for (int i = 0; i < 4; ++i) *(float4*)(wv + i * 4) = *(const float4*)(w + t * 16 + i * 4);
#pragma unroll
  for (int i = 0; i < 16; ++i) v[i] *= sc * wv[i];
  ushort_t* o = out + (long)row * HID + t * 16;
  *(uint4*)o       = pack8(v);
  *(uint4*)(o + 8) = pack8(v + 8);
}

// rmsnorm over merged-C cols [0,1536) (fp32, stride 2112) -> bf16 qa_n
__global__ void rms_qa_f32(const float* __restrict__ C,
                           const float* __restrict__ w,
                           ushort_t* __restrict__ out)
{
  int row = blockIdx.x, t = threadIdx.x;  // 192 threads, 8 elems each
  const float* xr = C + (long)row * NQAKV + t * 8;
  float v[8];
  *(float4*)(v)     = *(const float4*)(xr);
  *(float4*)(v + 4) = *(const float4*)(xr + 4);
  float ss = 0.f;
#pragma unroll
  for (int i = 0; i < 8; ++i) ss += v[i] * v[i];
#pragma unroll
  for (int o = 1; o < 64; o <<= 1) ss += __shfl_xor(ss, o);
  __shared__ float red[3];
  if ((t & 63) == 0) red[t >> 6] = ss;
  __syncthreads();
  float tot = red[0] + red[1] + red[2];
  float sc = rsqrtf(tot / (float)QLORA + EPS_RMS);
  float wv[8];
  *(float4*)(wv)     = *(const float4*)(w + t * 8);
  *(float4*)(wv + 4) = *(const float4*)(w + t * 8 + 4);
#pragma unroll
  for (int i = 0; i < 8; ++i) v[i] *= sc * wv[i];
  *(uint4*)(out + (long)row * QLORA + t * 8) = pack8(v);
}

// rmsnorm merged-C cols [1536,2048) (c_kv); rope cols [2048,2112) (k_pe).
__global__ void rms_ckv_rope_f32(const float* __restrict__ C,
                                 const float* __restrict__ w,
                                 const int* __restrict__ pos_ids,
                                 ushort_t* __restrict__ ckv_n,
                                 ushort_t* __restrict__ kpe,
                                 float* __restrict__ k_out)
{
  int row = blockIdx.x, t = threadIdx.x;  // 64 threads (1 wave)
  const float* xr = C + (long)row * NQAKV + QLORA;
  float v[8];
  *(float4*)(v)     = *(const float4*)(xr + t * 8);
  *(float4*)(v + 4) = *(const float4*)(xr + t * 8 + 4);
  float ss = 0.f;
#pragma unroll
  for (int i = 0; i < 8; ++i) ss += v[i] * v[i];
#pragma unroll
  for (int o = 1; o < 64; o <<= 1) ss += __shfl_xor(ss, o);
  float sc = rsqrtf(ss / (float)KVLORA + EPS_RMS);
  float wv[8];
  *(float4*)(wv)     = *(const float4*)(w + t * 8);
  *(float4*)(wv + 4) = *(const float4*)(w + t * 8 + 4);
  float ov[8];
#pragma unroll
  for (int i = 0; i < 8; ++i) ov[i] = v[i] * sc * wv[i];
  *(uint4*)(ckv_n + (long)row * KVLORA + t * 8) = pack8(ov);

  if (t < 32) {
    float e  = xr[512 + 2 * t];
    float od = xr[512 + 2 * t + 1];
    float p = (float)pos_ids[row];
    float inv = __builtin_exp2f(-((float)t / 32.f) * LOG2_10000);
    float ang = p * inv, sn, cs;
    sincosf(ang, &sn, &cs);
    float r1 = e * cs - od * sn;
    float r2 = od * cs + e * sn;
    kpe[(long)row * 64 + t]      = f2bf(r1);
    kpe[(long)row * 64 + 32 + t] = f2bf(r2);
#pragma unroll
    for (int h = 0; h < NHEAD; ++h) {
      float* kr = k_out + ((long)h * TOTK + PAST + row) * QHD + NOPE;
      kr[t] = r1;
      kr[32 + t] = r2;
    }
  }
}

// q post from fp32 split-K output: scale nope; rope+scale pe. (s,16,192) fp32
__global__ void qpost_f32(const float* __restrict__ q_raw,
                          const int* __restrict__ pos_ids,
                          ushort_t* __restrict__ q_bf)
{
  int row = blockIdx.x, t = threadIdx.x;  // 256
  const float* qr = q_raw + (long)row * 3072;
  ushort_t* qo = q_bf + (long)row * 3072;
  {
    int hh = t >> 4, c = t & 15;
    float v[8];
    *(float4*)(v)     = *(const float4*)(qr + hh * QHD + c * 8);
    *(float4*)(v + 4) = *(const float4*)(qr + hh * QHD + c * 8 + 4);
#pragma unroll
    for (int i = 0; i < 8; ++i) v[i] *= ATT_SCALE;
    *(uint4*)(qo + hh * QHD + c * 8) = pack8(v);
  }
  float p = (float)pos_ids[row];
#pragma unroll
  for (int it = 0; it < 2; ++it) {
    int slot = t + it * 256;
    int hh = slot >> 5, i = slot & 31;
    float e  = qr[hh * QHD + NOPE + 2 * i];
    float od = qr[hh * QHD + NOPE + 2 * i + 1];
    float inv = __builtin_exp2f(-((float)i / 32.f) * LOG2_10000);
    float ang = p * inv, sn, cs;
    sincosf(ang, &sn, &cs);
    qo[hh * QHD + NOPE + i]      = f2bf((e * cs - od * sn) * ATT_SCALE);
    qo[hh * QHD + NOPE + 32 + i] = f2bf((od * cs + e * sn) * ATT_SCALE);
  }
}

// kv post: split kv_raw (s, h*256 + [nope128|v128]) bf16 into fp32 k_out/v_out new rows
__global__ void kvpost_kernel(const ushort_t* __restrict__ kv_raw,
                              float* __restrict__ k_out,
                              float* __restrict__ v_out)
{
  int row = blockIdx.x, t = threadIdx.x;
  const ushort_t* kr = kv_raw + (long)row * 4096;
#pragma unroll
  for (int it = 0; it < 2; ++it) {
    int c = t + it * 256;
    int hh = c >> 5, cc = c & 31;
    float v[8];
    unpack8(*(const uint4*)(kr + c * 8), v);
    float* dst;
    if (cc < 16) dst = k_out + ((long)hh * TOTK + PAST + row) * QHD + cc * 8;
    else         dst = v_out + ((long)hh * TOTK + PAST + row) * VDIM + (cc - 16) * 8;
    floatx4 f0 = {v[0], v[1], v[2], v[3]};
    floatx4 f1 = {v[4], v[5], v[6], v[7]};
    *(floatx4*)dst = f0;
    *(floatx4*)(dst + 4) = f1;
  }
}

// past_k (fp32) -> k_out rows [0, PAST) (V half fused into buildV)
__global__ void past_kernel(const float* __restrict__ past_k,
                            float* __restrict__ k_out)
{
  long c = (long)blockIdx.x * 256 + threadIdx.x;  // chunk of 4 floats; 1,572,864 total
  float4 v = *(const float4*)(past_k + c * 4);
  long hh = c / 98304, rem = c % 98304;      // 2048*48 per head
  long s = rem / 48, cc = rem % 48;
  *(float4*)(k_out + (hh * (long)TOTK + s) * QHD + cc * 4) = v;
}

// Build attention-tiled bf16 K: granule g = ((h*64+kt)*24 + cc)*64 + ko
__global__ void buildK_kernel(const float* __restrict__ past_k,
                              const ushort_t* __restrict__ kv_raw,
                              const ushort_t* __restrict__ kpe,
                              ushort_t* __restrict__ Kc)
{
  long g = (long)blockIdx.x * 256 + threadIdx.x;  // < 1,572,864
  int ko = (int)(g & 63);
  long r = g >> 6;
  int cc = (int)(r % 24);
  long r2 = r / 24;
  int kt = (int)(r2 & 63);
  int hh = (int)(r2 >> 6);
  int key = kt * 64 + ko;
  uint4 val;
  if (key < PAST) {
    const float* src = past_k + ((long)hh * PAST + key) * QHD + cc * 8;
    float f[8];
    *(float4*)(f)     = *(const float4*)src;
    *(float4*)(f + 4) = *(const float4*)(src + 4);
    val = pack8(f);
  } else {
    int s = key - PAST;
    int d0 = cc * 8;
    if (d0 < NOPE) val = *(const uint4*)(kv_raw + (long)s * 4096 + hh * 256 + d0);
    else           val = *(const uint4*)(kpe + (long)s * 64 + (d0 - NOPE));
  }
  *(uint4*)(Kc + g * 8) = val;
}

// Build attention-tiled bf16 V^T (granule = (h,kt,vd,kchunk), row stride 9)
// + FUSED past_v -> v_out copy for past rows (writes coalesced across vd).
__global__ void buildV_kernel(const float* __restrict__ past_v,
                              const ushort_t* __restrict__ kv_raw,
                              ushort_t* __restrict__ Vc,
                              float* __restrict__ v_out)
{
  long tid = (long)blockIdx.x * 256 + threadIdx.x;  // < 1,048,576
  int vd = (int)(tid & 127);
  long r = tid >> 7;
  int kchunk = (int)(r & 7);
  long r2 = r >> 3;
  int kt = (int)(r2 & 63);
  int hh = (int)(r2 >> 6);
  int key0 = kt * 64 + kchunk * 8;
  __align__(16) ushort_t tmp[8];
  if (key0 < PAST) {
#pragma unroll
    for (int j = 0; j < 8; ++j) {
      float fv = past_v[((long)hh * PAST + key0 + j) * VDIM + vd];
      v_out[((long)hh * TOTK + key0 + j) * VDIM + vd] = fv;
      tmp[j] = f2bf(fv);
    }
  } else {
    int s = key0 - PAST;
#pragma unroll
    for (int j = 0; j < 8; ++j)
      tmp[j] = kv_raw[(long)(s + j) * 4096 + hh * 256 + NOPE + vd];
  }
  *(uint4*)(Vc + ((((long)hh * 64 + kt) * 128 + vd) * 9 + kchunk) * 8) = *(uint4*)tmp;
}

// ---------------------------------------------------------------------------
// Flash attention, split-K x3 + T13 defer-max (R4/R6-verified, unchanged).
// ---------------------------------------------------------------------------
__global__ __launch_bounds__(256, 3) void attn_kernel(
    const ushort_t* __restrict__ qb,        // (s,16,192) bf16, pre-scaled
    const ushort_t* __restrict__ Kc,        // tiled bf16
    const ushort_t* __restrict__ Vc,        // tiled bf16 (V^T, padded rows)
    const float* __restrict__ attn_mask,    // (2048,4096) fp32
    ushort_t* __restrict__ opart,           // (3,16,2048,128) bf16 partial O
    float* __restrict__ ml)                 // (3,16,2048) float2 {m,l}
{
  __shared__ __align__(16) ushort_t KtL[1536 * 8];
  __shared__ __align__(16) ushort_t VtL[1152 * 8];
  __shared__ __align__(16) ushort_t Pl[4 * 16 * 72];

  int t = threadIdx.x, lane = t & 63, wave = t >> 6;
  int lrow = lane & 15, quad = lane >> 4;
  int lb = blockIdx.x;                            // [0, 1536)
  int xcd = lb & 7, j = lb >> 3;                  // j in [0, 192)
  int h = xcd + 8 * (j / 96);
  int rem = j % 96;
  int sec = rem >> 5;                             // 0..2
  int q0 = (rem & 31) * 64;
  int kt_beg = (sec == 0) ? 0 : (sec == 1 ? 22 : 43);
  int kt_end = (sec == 0) ? 22 : (sec == 1 ? 43 : 64);
  int qrow_a = q0 + wave * 16 + lrow;
  int qrow_c = q0 + wave * 16 + quad * 4;

  short8 aq[6];
  const ushort_t* qp = qb + ((long)qrow_a * 16 + h) * QHD + quad * 8;
#pragma unroll
  for (int kc = 0; kc < 6; ++kc) aq[kc] = *(const short8*)(qp + kc * 32);

  float m_r[4], l_r[4];
  floatx4 cacc[8];
#pragma unroll
  for (int r = 0; r < 4; ++r) { m_r[r] = -1e30f; l_r[r] = 0.f; }
#pragma unroll
  for (int v = 0; v < 8; ++v) cacc[v] = (floatx4)0.f;

  const ushort_t* Kbase = Kc + (long)h * 64 * 1536 * 8;
  const ushort_t* Vbase = Vc + (long)h * 64 * 1152 * 8;

  for (int kt2 = kt_beg; kt2 < kt_end; ++kt2) {
    const ushort_t* ks = Kbase + (long)kt2 * 1536 * 8;
#pragma unroll
    for (int i = 0; i < 6; ++i) {
      int s = i * 256 + t;
      *(uint4*)&KtL[s * 8] = *(const uint4*)(ks + (long)s * 8);
    }
    const ushort_t* vs = Vbase + (long)kt2 * 1152 * 8;
#pragma unroll
    for (int i = 0; i < 5; ++i) {
      int s = i * 256 + t;
      if (s < 1152) *(uint4*)&VtL[s * 8] = *(const uint4*)(vs + (long)s * 8);
    }
    __syncthreads();

    floatx4 sacc[4];
#pragma unroll
    for (int nt = 0; nt < 4; ++nt) sacc[nt] = (floatx4)0.f;
    __builtin_amdgcn_s_setprio(1);
#pragma unroll
    for (int kc = 0; kc < 6; ++kc) {
#pragma unroll
      for (int nt = 0; nt < 4; ++nt) {
        short8 bk = *(const short8*)&KtL[(((kc * 4 + quad) * 64) + nt * 16 + lrow) * 8];
        sacc[nt] = __builtin_amdgcn_mfma_f32_16x16x32_bf16(aq[kc], bk, sacc[nt], 0, 0, 0);
      }
    }
    __builtin_amdgcn_s_setprio(0);

    int kbase = kt2 * 64;
    float sv[4][4];
#pragma unroll
    for (int nt = 0; nt < 4; ++nt)
#pragma unroll
      for (int r = 0; r < 4; ++r)
        sv[nt][r] = sacc[nt][r] +
                    attn_mask[(long)(qrow_c + r) * TOTK + kbase + nt * 16 + lrow];

    float mxv[4]; int need = 0;
#pragma unroll
    for (int r = 0; r < 4; ++r) {
      float mx = fmaxf(fmaxf(sv[0][r], sv[1][r]), fmaxf(sv[2][r], sv[3][r]));
      mx = fmaxf(mx, __shfl_xor(mx, 1));
      mx = fmaxf(mx, __shfl_xor(mx, 2));
      mx = fmaxf(mx, __shfl_xor(mx, 4));
      mx = fmaxf(mx, __shfl_xor(mx, 8));
      mxv[r] = mx;
      need |= (mx > m_r[r] + 8.f) ? 1 : 0;
    }
    float alpha[4] = {1.f, 1.f, 1.f, 1.f};
    if (__any(need)) {
#pragma unroll
      for (int r = 0; r < 4; ++r) {
        float mn = fmaxf(m_r[r], mxv[r]);
        alpha[r] = __builtin_exp2f((m_r[r] - mn) * LOG2E);
        m_r[r] = mn;
      }
#pragma unroll
      for (int v = 0; v < 8; ++v) {
        floatx4 c = cacc[v];
        c[0] *= alpha[0]; c[1] *= alpha[1]; c[2] *= alpha[2]; c[3] *= alpha[3];
        cacc[v] = c;
      }
    }
#pragma unroll
    for (int r = 0; r < 4; ++r) {
      float rs = 0.f;
#pragma unroll
      for (int nt = 0; nt < 4; ++nt) {
        float p = __builtin_exp2f((sv[nt][r] - m_r[r]) * LOG2E);
        sv[nt][r] = p;
        rs += p;
      }
      rs += __shfl_xor(rs, 1);
      rs += __shfl_xor(rs, 2);
      rs += __shfl_xor(rs, 4);
      rs += __shfl_xor(rs, 8);
      l_r[r] = l_r[r] * alpha[r] + rs;
    }

    ushort_t* pw = &Pl[wave * 16 * 72];
#pragma unroll
    for (int nt = 0; nt < 4; ++nt)
#pragma unroll
      for (int r = 0; r < 4; ++r)
        pw[(quad * 4 + r) * 72 + nt * 16 + lrow] = f2bf(sv[nt][r]);

    const ushort_t* pr = &Pl[wave * 16 * 72];
    short8 ap[2];
#pragma unroll
    for (int kc = 0; kc < 2; ++kc)
      ap[kc] = *(const short8*)(pr + lrow * 72 + kc * 32 + quad * 8);
    __builtin_amdgcn_s_setprio(1);
#pragma unroll
    for (int kc = 0; kc < 2; ++kc) {
#pragma unroll
      for (int v = 0; v < 8; ++v) {
        short8 bv = *(const short8*)&VtL[(((v * 16 + lrow) * 9) + kc * 4 + quad) * 8];
        cacc[v] = __builtin_amdgcn_mfma_f32_16x16x32_bf16(ap[kc], bv, cacc[v], 0, 0, 0);
      }
    }
    __builtin_amdgcn_s_setprio(0);
    __syncthreads();
  }

  long obase = (long)(sec * 16 + h) * 2048 + qrow_c;
#pragma unroll
  for (int v = 0; v < 8; ++v)
#pragma unroll
    for (int r = 0; r < 4; ++r)
      opart[(obase + r) * 128 + v * 16 + lrow] = f2bf(cacc[v][r]);
  if (lrow == 0) {
#pragma unroll
    for (int r = 0; r < 4; ++r) {
      float* mp = ml + (obase + r) * 2;
      mp[0] = m_r[r];
      mp[1] = l_r[r];
    }
  }
}

// Merge 3 split-K partials
__global__ void combine_kernel(const ushort_t* __restrict__ opart,
                               const float* __restrict__ ml,
                               ushort_t* __restrict__ ctx)
{
  int t = threadIdx.x;
  int gr = blockIdx.x * 16 + (t >> 4);       // [0, 32768): h*2048 + qrow
  int h = gr >> 11, qrow = gr & 2047;
  int dc = (t & 15) * 8;
  float m[3], l[3];
#pragma unroll
  for (int s = 0; s < 3; ++s) {
    const float* p = ml + ((long)(s * 16 + h) * 2048 + qrow) * 2;
    m[s] = p[0]; l[s] = p[1];
  }
  float M = fmaxf(fmaxf(m[0], m[1]), m[2]);
  float aa[3], L = 0.f;
#pragma unroll
  for (int s = 0; s < 3; ++s) {
    aa[s] = __builtin_exp2f((m[s] - M) * LOG2E);
    L += aa[s] * l[s];
  }
  float inv = 1.f / L;
  float acc[8] = {0.f, 0.f, 0.f, 0.f, 0.f, 0.f, 0.f, 0.f};
#pragma unroll
  for (int s = 0; s < 3; ++s) {
    uint4 c = *(const uint4*)(opart + ((long)(s * 16 + h) * 2048 + qrow) * 128 + dc);
    float f[8];
    unpack8(c, f);
#pragma unroll
    for (int i = 0; i < 8; ++i) acc[i] += aa[s] * f[i];
  }
  float outv[8];
#pragma unroll
  for (int i = 0; i < 8; ++i) outv[i] = acc[i] * inv;
  *(uint4*)(ctx + (long)qrow * 2048 + h * 128 + dc) = pack8(outv);
}

// ---------------------------------------------------------------------------
extern "C" void kernel_launch(void* const* d_in, const int* in_sizes, int n_in,
                              void* d_out, int out_size, void* d_ws, size_t ws_size,
                              hipStream_t stream)
{
  const float* hidden   = (const float*)d_in[0];
  const int*   pos      = (const int*)d_in[1];
  const float* mask     = (const float*)d_in[2];
  const float* past_k   = (const float*)d_in[3];
  const float* past_v   = (const float*)d_in[4];
  const float* w_in_ln  = (const float*)d_in[5];
  const float* w_qa     = (const float*)d_in[6];
  const float* w_qa_ln  = (const float*)d_in[7];
  const float* w_qb     = (const float*)d_in[8];
  const float* w_kva    = (const float*)d_in[9];
  const float* w_kva_ln = (const float*)d_in[10];
  const float* w_kvb    = (const float*)d_in[11];
  const float* w_o      = (const float*)d_in[12];

  float* out0  = (float*)d_out;                 // (2048, 5120)
  float* k_out = out0 + 10485760;               // (16, 4096, 192)
  float* v_out = k_out + 12582912;              // (16, 4096, 128)

  char* ws = (char*)d_ws;
  // Liveness-checked layout (epochs E1..E13 in session journal; peak 100 MiB):
  //  [0,         9.4M)  wqb_bf
  //  [9.4M,     13.6M)  wkvb_bf
  //  [13.6M,    26.2M)  qa_n (E4-E5) -> q_bf (E6-attn)
  //  [26.2M,    26.5M)  kpe
  //  [26.5M,    28.6M)  ckv_n
  //  [28.6M,    53.7M)  wqakva_bf -> Cq3 fp32 -> Vc -> ctx
  //  [53.7M,    78.9M)  x_bf -> Kc -> wo_bf
  //  [78.9M,   104.1M)  Cqakv fp32 -> kv_raw bf16 -> opart
  //  [104.1M,  104.9M)  mlbuf
  ushort_t* wqb_bf    = (ushort_t*)(ws + 0);             //  9,437,184
  ushort_t* wkvb_bf   = (ushort_t*)(ws + 9437184);       //  4,194,304
  ushort_t* qa_n      = (ushort_t*)(ws + 13631488);      //  6,291,456
  ushort_t* q_bf      = (ushort_t*)(ws + 13631488);      // 12,582,912
  ushort_t* kpe       = (ushort_t*)(ws + 26214400);      //    262,144
  ushort_t* ckv_n     = (ushort_t*)(ws + 26476544);      //  2,097,152
  ushort_t* wqakva_bf = (ushort_t*)(ws + 28573696);      // 21,626,880
  float*    Cq3       = (float*)   (ws + 28573696);      // 25,165,824
  ushort_t* Vc        = (ushort_t*)(ws + 28573696);      // 18,874,368
  ushort_t* ctx       = (ushort_t*)(ws + 28573696);      //  8,388,608
  ushort_t* x_bf      = (ushort_t*)(ws + 53739520);      // 20,971,520
  ushort_t* Kc        = (ushort_t*)(ws + 53739520);      // 25,165,824
  ushort_t* wo_bf     = (ushort_t*)(ws + 53739520);      // 20,971,520
  float*    Cqakv     = (float*)   (ws + 78905344);      // 17,301,504
  ushort_t* kv_raw    = (ushort_t*)(ws + 78905344);      // 16,777,216
  ushort_t* opart     = (ushort_t*)(ws + 78905344);      // 25,165,824
  float*    mlbuf     = (float*)   (ws + 104071168);     //    786,432

  // E1: weight bf16 staging
  cvt_kernel<<<dim3(3840), dim3(256), 0, stream>>>(w_qa, wqakva_bf);            // 1536x5120
  cvt_kernel<<<dim3(1440), dim3(256), 0, stream>>>(w_kva, wqakva_bf + 7864320); // 576x5120
  cvt_kernel<<<dim3(2304), dim3(256), 0, stream>>>(w_qb, wqb_bf);               // 3072x1536
  cvt_kernel<<<dim3(1024), dim3(256), 0, stream>>>(w_kvb, wkvb_bf);             // 4096x512

  // E2
  zero4_kernel<<<dim3(4224), dim3(256), 0, stream>>>((uint4*)Cqakv);            // 17,301,504 B
  rms_in_kernel<<<dim3(2048), dim3(320), 0, stream>>>(hidden, w_in_ln, x_bf);

  // E3: merged qa|kva projection, split-K x3 -> 816 blocks (uneven 54/53/53)
  gemm_splitk<<<dim3(17, 16, 3), dim3(256), 0, stream>>>(x_bf, wqakva_bf, Cqakv,
                                                         2048, NQAKV, 5120);

  // E4
  rms_qa_f32<<<dim3(2048), dim3(192), 0, stream>>>(Cqakv, w_qa_ln, qa_n);
  rms_ckv_rope_f32<<<dim3(2048), dim3(64), 0, stream>>>(Cqakv, w_kva_ln, pos,
                                                        ckv_n, kpe, k_out);

  // E5: q_b projection, split-K x2 -> 768 blocks (was 384 = 1.5/CU)
  zero4_kernel<<<dim3(6144), dim3(256), 0, stream>>>((uint4*)Cq3);              // 25,165,824 B
  gemm_splitk<<<dim3(24, 16, 2), dim3(256), 0, stream>>>(qa_n, wqb_bf, Cq3,
                                                         2048, 3072, 1536);
  // E6
  qpost_f32<<<dim3(2048), dim3(256), 0, stream>>>(Cq3, pos, q_bf);

  // E7: kv_b projection (grid 512 = 2.0/CU, K=512 short: keep unsplit bf16)
  gemm_bt<<<dim3(32, 16), dim3(256), 0, stream>>>(ckv_n, wkvb_bf, kv_raw, (float*)nullptr,
                                                  (const float*)nullptr, 0.f, 2048, 4096, 512);
  // E8
  kvpost_kernel<<<dim3(2048), dim3(256), 0, stream>>>(kv_raw, k_out, v_out);
  past_kernel<<<dim3(6144), dim3(256), 0, stream>>>(past_k, k_out);

  // E9/E10 (buildV fuses past_v -> v_out copy)
  buildK_kernel<<<dim3(6144), dim3(256), 0, stream>>>(past_k, kv_raw, kpe, Kc);
  buildV_kernel<<<dim3(4096), dim3(256), 0, stream>>>(past_v, kv_raw, Vc, v_out);

  // E11/E12
  attn_kernel<<<dim3(1536), dim3(256), 0, stream>>>(q_bf, Kc, Vc, mask, opart, mlbuf);
  combine_kernel<<<dim3(2048), dim3(256), 0, stream>>>(opart, mlbuf, ctx);

  // E13: output projection, split-K x2 -> 1280 blocks; residual pre-init
  cvt_kernel<<<dim3(5120), dim3(256), 0, stream>>>(w_o, wo_bf);                 // 5120x2048
  resid_init_kernel<<<dim3(10240), dim3(256), 0, stream>>>(hidden, out0);
  gemm_splitk<<<dim3(40, 16, 2), dim3(256), 0, stream>>>(ctx, wo_bf, out0,
                                                         2048, 5120, 2048);
}